// Round 10
// baseline (322.627 us; speedup 1.0000x reference)
//
#include <hip/hip_runtime.h>
#include <hip/hip_bf16.h>

#define Bn 8
#define Qn 300
#define Pn 5
#define RSn 256
#define QSn 768
#define NCn 396
#define MTOT 10880
#define THRL -1.3862943611198906f   // log(0.2/0.8): sigmoid(x)>0.2 <=> x>THRL

typedef __attribute__((ext_vector_type(8))) short short8;
typedef __attribute__((ext_vector_type(4))) float float4v;

__device__ inline float wred(float v){
  #pragma unroll
  for (int off = 32; off; off >>= 1) v += __shfl_xor(v, off);
  return v;
}

__device__ __forceinline__ unsigned short f2bf(float f){
  union { float f; unsigned int u; } c; c.f = f;
  return (unsigned short)((c.u + 0x7FFF + ((c.u >> 16) & 1)) >> 16);   // RNE
}

// =====================================================================
// D1: k_front — [0,768): convW f32 -> bf16 swizzled Wswz[s][kc][lk][n][8]
//               768: mask detect ; [769,809): query pooling ;
//               [809,821): zero ctxsum+hpre ; [821,825): zero out
// Query pooling: q-loop split across the 4 waves (75 q each) + 15x4
// fully-unrolled load block -> 5 latency rounds (was 25). LDS combine.
// =====================================================================
__global__ __launch_bounds__(256, 4) void k_front(
    const float* cw0, const float* cw1, const float* cw2, const float* cw3,
    short* Wswz, const int* __restrict__ mk0, int* det,
    const float* __restrict__ pl, const float* __restrict__ hs,
    float* pooled, int* flags, float* ctxsum, float* outz){
  int bx = blockIdx.x;
  int t = threadIdx.x;
  if (bx < 768){
    int s = bx / 192;
    int linear = (bx % 192)*256 + t;
    int q = linear & 63, n = linear >> 6;
    const float* src = (s==0)?cw0:(s==1)?cw1:(s==2)?cw2:cw3;
    float4 f = *(const float4*)(src + (size_t)n*256 + q*4);
    int kc = q >> 3, lk = (q >> 1) & 3, e0 = (q & 1)*4;
    short* dst = Wswz + ((size_t)(s*8 + kc))*24576 + lk*6144 + n*8 + e0;
    short4 sv;
    sv.x = (short)f2bf(f.x); sv.y = (short)f2bf(f.y);
    sv.z = (short)f2bf(f.z); sv.w = (short)f2bf(f.w);
    *(short4*)dst = sv;
    return;
  }
  if (bx == 768){
    __shared__ int r0[4], r1[4];
    const int* mm = mk0 + t*32;
    int d0 = 0, d1 = 0;
    #pragma unroll 8
    for (int i = 0; i < 32; ++i){
      int v = mm[i];
      d0 |= (v != 0 && v != 1);
      d1 |= (v != 0 && v != 0x3F800000);
    }
    unsigned long long bal0 = __ballot(d0), bal1 = __ballot(d1);
    int wid = t >> 6;
    if ((t & 63) == 0){ r0[wid] = (bal0 != 0ull); r1[wid] = (bal1 != 0ull); }
    __syncthreads();
    if (t == 0){
      det[0] = r0[0] | r0[1] | r0[2] | r0[3];
      det[1] = r1[0] | r1[1] | r1[2] | r1[3];
    }
    return;
  }
  if (bx >= 821){
    int idx = ((bx - 821)*256 + t)*4;
    if (idx < Bn*NCn) *(float4*)(outz + idx) = (float4){0.f,0.f,0.f,0.f};
    return;
  }
  if (bx >= 809){
    int idx = ((bx - 809)*256 + t)*4;      // zero ctxsum(6144)+hpre(6144)
    *(float4*)(ctxsum + idx) = (float4){0.f,0.f,0.f,0.f};
    return;
  }
  // ---- query pooling: wave w handles q in [w*75, w*75+75); lane l owns
  // channels {l, l+64, l+128, l+192}. 5 rounds of 15q x 4ch = 60
  // independent loads; LDS partial-sum combine across waves.
  __shared__ float msk[Qn];
  __shared__ float psum[4][256];
  __shared__ float pcnt[4];
  int bb = (bx - 769) / Pn, p = (bx - 769) % Pn;
  for (int q = t; q < Qn; q += 256)
    msk[q] = (pl[(bb*Qn + q)*Pn + p] > THRL) ? 1.f : 0.f;
  __syncthreads();
  int wv = t >> 6, lane = t & 63;
  int qbase = wv * 75;
  const float* hbw = hs + (size_t)bb*Qn*RSn + lane;
  float a0 = 0.f, a1 = 0.f, a2 = 0.f, a3 = 0.f, cnt = 0.f;
  for (int r = 0; r < 5; ++r){
    #pragma unroll
    for (int i = 0; i < 15; ++i){
      int q = qbase + r*15 + i;
      float m = msk[q];
      cnt += m;
      const float* row = hbw + (size_t)q*RSn;
      a0 = fmaf(m, row[0],   a0);
      a1 = fmaf(m, row[64],  a1);
      a2 = fmaf(m, row[128], a2);
      a3 = fmaf(m, row[192], a3);
    }
  }
  psum[wv][lane      ] = a0;
  psum[wv][lane + 64 ] = a1;
  psum[wv][lane + 128] = a2;
  psum[wv][lane + 192] = a3;
  if (lane == 0) pcnt[wv] = cnt;
  __syncthreads();
  float ssum = psum[0][t] + psum[1][t] + psum[2][t] + psum[3][t];
  float ctot = pcnt[0] + pcnt[1] + pcnt[2] + pcnt[3];
  pooled[(bb*Pn + p)*RSn + t] = (ctot > 0.f) ? ssum / ctot : 0.f;
  if (t == 0) flags[bb*Pn + p] = (ctot > 0.f) ? 1 : 0;
}

// =====================================================================
// D2: k_pgemm — blocks [0,680): fused pool + MFMA GEMM + bias + LN + token-sum
//               blocks [680,728): query tokens + LN -> qt
// Round-8 GEMM shape (M=16, 4 waves x 12 nf — best measured) + round-9's
// verified float4 token-pair pool (32x16B loads/thread, fully unrolled,
// was 64x8B at unroll 2).
// =====================================================================
__global__ __launch_bounds__(256, 3) void k_pgemm(
    const float* fe0, const float* po0, const void* ma0,
    const float* fe1, const float* po1, const void* ma1,
    const float* fe2, const float* po2, const void* ma2,
    const float* fe3, const float* po3, const void* ma3,
    const int* __restrict__ det, const short* __restrict__ Wswz,
    const float* cb0, const float* cb1, const float* cb2, const float* cb3,
    const float* lg0, const float* lb0, const float* lg1, const float* lb1,
    const float* lg2, const float* lb2, const float* lg3, const float* lb3,
    float* __restrict__ ctxsum,
    const float* __restrict__ lq, const float* __restrict__ Wq,
    const float* __restrict__ bq, const float* __restrict__ qng,
    const float* __restrict__ qnb, const float* __restrict__ pooled,
    const int* __restrict__ flags, float* qt){
  __shared__ short As[16*264];        // 8.25 KB A-tile [m][k], pitch 264
  __shared__ float imls[16];
  __shared__ float lsum[4][16], lsq[4][16];
  __shared__ float pq[256];
  __shared__ float s1s[4], s2s[4];
  int blk = blockIdx.x;
  int t = threadIdx.x;

  if (blk >= 680){
    // ---- query tokens + LN
    int qbx = blk - 680;
    int b = qbx / 6, j = qbx % 6;
    float v0 = lq[j*QSn + t], v1 = lq[j*QSn + t + 256], v2 = lq[j*QSn + t + 512];
    int any = flags[b*Pn] | flags[b*Pn+1] | flags[b*Pn+2] | flags[b*Pn+3] | flags[b*Pn+4];
    if (j > 0 && any){
      pq[t] = pooled[(b*Pn + (j-1))*RSn + t];
      __syncthreads();
      float a0 = 0.f, a1 = 0.f, a2 = 0.f;
      #pragma unroll 8
      for (int c = 0; c < RSn; ++c){
        float pv = pq[c];
        a0 = fmaf(pv, Wq[c*QSn + t      ], a0);
        a1 = fmaf(pv, Wq[c*QSn + t + 256], a1);
        a2 = fmaf(pv, Wq[c*QSn + t + 512], a2);
      }
      v0 += a0 + bq[t]; v1 += a1 + bq[t+256]; v2 += a2 + bq[t+512];
    }
    float sm = v0 + v1 + v2, sq = v0*v0 + v1*v1 + v2*v2;
    sm = wred(sm); sq = wred(sq);
    int wid = t >> 6, lane = t & 63;
    if (lane == 0){ s1s[wid] = sm; s2s[wid] = sq; }
    __syncthreads();
    float S  = s1s[0] + s1s[1] + s1s[2] + s1s[3];
    float SQ = s2s[0] + s2s[1] + s2s[2] + s2s[3];
    float mu = S * (1.f/QSn), var = SQ * (1.f/QSn) - mu*mu;
    float rs = rsqrtf(var + 1e-5f);
    float* o = qt + (b*6 + j)*QSn;
    o[t      ] = (v0 - mu)*rs*qng[t      ] + qnb[t      ];
    o[t + 256] = (v1 - mu)*rs*qng[t + 256] + qnb[t + 256];
    o[t + 512] = (v2 - mu)*rs*qng[t + 512] + qnb[t + 512];
    return;
  }

  int m0 = blk * 16;
  int s, H, OWlog, b0;
  const float *F, *Pp; const void* M;
  const float *CB, *LG, *LB;
  if (m0 < 8192){ s=0; F=fe0; Pp=po0; M=ma0; H=64; OWlog=5; b0=m0>>10;
                  CB=cb0; LG=lg0; LB=lb0; }
  else if (m0 < 10240){ s=1; F=fe1; Pp=po1; M=ma1; H=32; OWlog=4; b0=(m0-8192)>>8;
                  CB=cb1; LG=lg1; LB=lb1; }
  else if (m0 < 10752){ s=2; F=fe2; Pp=po2; M=ma2; H=16; OWlog=3; b0=(m0-10240)>>6;
                  CB=cb2; LG=lg2; LB=lb2; }
  else { s=3; F=fe3; Pp=po3; M=ma3; H=8; OWlog=2; b0=(m0-10752)>>4;
                  CB=cb3; LG=lg3; LB=lb3; }
  int HH = H*H;
  int OWm = (H >> 1) - 1;
  int mode = (det[0] == 0) ? 0 : ((det[1] == 0) ? 2 : 1);

  // ---- token-pair geometry: slotp = t&7 (8 pairs), cg = t>>3 (0..31)
  int slotp = t & 7;
  int cg = t >> 3;
  int mA = m0 + slotp*2;
  int ltl;
  if (s == 0)      ltl = mA & 1023;
  else if (s == 1) ltl = mA & 255;
  else if (s == 2) ltl = mA & 63;
  else             ltl = mA & 15;
  int ph = ltl >> OWlog, pw = ltl & OWm;   // pw even
  int i00 = ph*2*H + pw*2;                 // multiple of 4 -> float4 aligned
  int mbase = b0*HH;

  // ---- mask weights for both tokens of the pair (16B-span reads)
  float w0A,w1A,w2A,w3A, w0B,w1B,w2B,w3B;
  if (mode == 0){
    const int* Mi = (const int*)M + mbase + i00;
    int4 ma = *(const int4*)(Mi);
    int4 mb = *(const int4*)(Mi + H);
    w0A = ma.x?0.f:1.f; w1A = ma.y?0.f:1.f; w2A = mb.x?0.f:1.f; w3A = mb.y?0.f:1.f;
    w0B = ma.z?0.f:1.f; w1B = ma.w?0.f:1.f; w2B = mb.z?0.f:1.f; w3B = mb.w?0.f:1.f;
  } else if (mode == 1){
    const unsigned char* Mb = (const unsigned char*)M + mbase + i00;
    uchar4 av = *(const uchar4*)(Mb);
    uchar4 bv = *(const uchar4*)(Mb + H);
    w0A = av.x?0.f:1.f; w1A = av.y?0.f:1.f; w2A = bv.x?0.f:1.f; w3A = bv.y?0.f:1.f;
    w0B = av.z?0.f:1.f; w1B = av.w?0.f:1.f; w2B = bv.z?0.f:1.f; w3B = bv.w?0.f:1.f;
  } else {
    const float* Mf = (const float*)M + mbase + i00;
    float4 ma = *(const float4*)(Mf);
    float4 mb = *(const float4*)(Mf + H);
    w0A = 1.f-ma.x; w1A = 1.f-ma.y; w2A = 1.f-mb.x; w3A = 1.f-mb.y;
    w0B = 1.f-ma.z; w1B = 1.f-ma.w; w2B = 1.f-mb.z; w3B = 1.f-mb.w;
  }
  float msA = w0A+w1A+w2A+w3A, msB = w0B+w1B+w2B+w3B;
  float imA = 1.f / fmaxf(msA*0.25f, 1e-6f);
  float imB = 1.f / fmaxf(msB*0.25f, 1e-6f);
  float scA = 0.25f*imA, scB = 0.25f*imB;
  if (t < 8){ imls[t*2] = imA; imls[t*2 + 1] = imB; }

  // ---- pool 256 channels into As[m][k]: 8 fully-unrolled rounds of
  // 4 float4 loads (token-pair: xA from .x/.y, xB from .z/.w)
  {
    size_t base = (size_t)(b0*256 + cg)*HH + i00;
    const float* Fp = F + base;
    const float* Pq2 = Pp + base;
    const size_t stride = (size_t)32*HH;
    int rowA = slotp*2*264, rowB = rowA + 264;
    #pragma unroll
    for (int r = 0; r < 8; ++r){
      float4 f0 = *(const float4*)(Fp);
      float4 f1 = *(const float4*)(Fp + H);
      float4 p0 = *(const float4*)(Pq2);
      float4 p1 = *(const float4*)(Pq2 + H);
      float xA = (f0.x+p0.x)*w0A + (f0.y+p0.y)*w1A + (f1.x+p1.x)*w2A + (f1.y+p1.y)*w3A;
      float xB = (f0.z+p0.z)*w0B + (f0.w+p0.w)*w1B + (f1.z+p1.z)*w2B + (f1.w+p1.w)*w3B;
      As[rowA + cg + r*32] = (short)f2bf(xA*scA);
      As[rowB + cg + r*32] = (short)f2bf(xB*scB);
      Fp += stride; Pq2 += stride;
    }
  }
  __syncthreads();

  // ---- A fragments to registers
  int wid = t >> 6, l = t & 63;
  int lm = l & 15, lk = l >> 4;
  int nfb = wid * 12;
  short8 aReg[8];
  #pragma unroll
  for (int kc = 0; kc < 8; ++kc)
    aReg[kc] = *(const short8*)(As + lm*264 + kc*32 + lk*8);

  float4v acc[12];
  #pragma unroll
  for (int nf = 0; nf < 12; ++nf) acc[nf] = (float4v){0.f,0.f,0.f,0.f};

  // ---- K loop: B fragments straight from L2 (pre-swizzled, 16B/lane)
  const short* Bb = Wswz + ((size_t)(s*8))*24576 + lk*6144 + nfb*128 + lm*8;
  #pragma unroll
  for (int kc = 0; kc < 8; ++kc){
    const short* bp = Bb + kc*24576;
    #pragma unroll
    for (int nf = 0; nf < 12; ++nf){
      short8 bf = *(const short8*)(bp + nf*128);
      acc[nf] = __builtin_amdgcn_mfma_f32_16x16x32_bf16(aReg[kc], bf, acc[nf], 0, 0, 0);
    }
  }

  // ---- epilogue: bias (via LDS im), per-row LN, token-sum -> ctxsum
  float im4[4];
  #pragma unroll
  for (int r = 0; r < 4; ++r) im4[r] = imls[lk*4 + r];

  float sum[4] = {0,0,0,0}, sq[4] = {0,0,0,0};
  #pragma unroll
  for (int nf = 0; nf < 12; ++nf){
    float cbv = CB[(nfb+nf)*16 + lm];
    #pragma unroll
    for (int r = 0; r < 4; ++r){
      float p = acc[nf][r] + cbv*im4[r];
      acc[nf][r] = p;
      sum[r] += p;
      sq[r] = fmaf(p, p, sq[r]);
    }
  }
  #pragma unroll
  for (int r = 0; r < 4; ++r){
    #pragma unroll
    for (int off = 1; off < 16; off <<= 1){
      sum[r] += __shfl_xor(sum[r], off);
      sq[r]  += __shfl_xor(sq[r],  off);
    }
  }
  if (lm == 0){
    #pragma unroll
    for (int r = 0; r < 4; ++r){
      lsum[wid][lk*4 + r] = sum[r];
      lsq[wid][lk*4 + r]  = sq[r];
    }
  }
  __syncthreads();
  float mu[4], rs[4];
  #pragma unroll
  for (int r = 0; r < 4; ++r){
    int row = lk*4 + r;
    float S  = lsum[0][row] + lsum[1][row] + lsum[2][row] + lsum[3][row];
    float SQ = lsq[0][row]  + lsq[1][row]  + lsq[2][row]  + lsq[3][row];
    mu[r] = S * (1.f/768.f);
    float var = SQ * (1.f/768.f) - mu[r]*mu[r];
    rs[r] = rsqrtf(var + 1e-5f);
  }
  #pragma unroll
  for (int nf = 0; nf < 12; ++nf){
    int n = (nfb+nf)*16 + lm;
    float g = LG[n], bv = LB[n];
    float tv = 0.f;
    #pragma unroll
    for (int r = 0; r < 4; ++r)
      tv += (acc[nf][r] - mu[r]) * rs[r];
    tv = tv*g + 4.f*bv;
    tv += __shfl_xor(tv, 16); tv += __shfl_xor(tv, 32);
    if (lk == 0)
      atomicAdd(&ctxsum[b0*768 + n], tv);
  }
}

// =====================================================================
// D3: k_hpre — hpre += v @ W1 (+b1). Grid 96 = 24n(32col) x 4k(192c).
// 16 partial accumulators (round-8 ILP win).
// =====================================================================
__global__ void k_hpre(const float* __restrict__ qt, const float* __restrict__ ctxsum,
                       const float* __restrict__ W1, const float* __restrict__ b1,
                       float* __restrict__ hpre){
  __shared__ float vsh[Bn][192];
  int nc = blockIdx.x % 24, kc = blockIdx.x / 24;
  int n0 = nc*32, c0 = kc*192;
  int t = threadIdx.x;
  for (int i = t; i < Bn*192; i += 256){
    int b = i / 192, cl = i - b*192;
    int c = c0 + cl;
    const float* q = qt + (size_t)b*6*768;
    float pm = q[768+c] + q[2*768+c] + q[3*768+c] + q[4*768+c] + q[5*768+c];
    vsh[b][cl] = q[c] + 0.2f*pm + ctxsum[b*768 + c]*(1.f/680.f);
  }
  __syncthreads();
  int ow = t & 31, bi = t >> 5;
  int o = n0 + ow;
  const float* w = W1 + (size_t)c0*768 + o;
  float pacc[16];
  #pragma unroll
  for (int i = 0; i < 16; ++i) pacc[i] = 0.f;
  for (int cl = 0; cl < 192; cl += 16){
    #pragma unroll
    for (int i = 0; i < 16; ++i)
      pacc[i] = fmaf(vsh[bi][cl + i], w[(size_t)(cl + i)*768], pacc[i]);
  }
  float acc = ((pacc[0]+pacc[1])+(pacc[2]+pacc[3])) + ((pacc[4]+pacc[5])+(pacc[6]+pacc[7]))
            + ((pacc[8]+pacc[9])+(pacc[10]+pacc[11])) + ((pacc[12]+pacc[13])+(pacc[14]+pacc[15]));
  if (kc == 0) acc += b1[o];
  atomicAdd(&hpre[bi*768 + o], acc);
}

// =====================================================================
// D4: k_out — out += relu(hpre) @ W2 (+b2). Grid 52 = 13n(32) x 4k(192).
// =====================================================================
__global__ void k_out(const float* __restrict__ hpre, const float* __restrict__ W2,
                      const float* __restrict__ b2, float* __restrict__ out){
  __shared__ float hsh[Bn][192];
  int nc = blockIdx.x % 13, kc = blockIdx.x / 13;
  int n0 = nc*32, c0 = kc*192;
  int t = threadIdx.x;
  for (int i = t; i < Bn*192; i += 256){
    int b = i / 192, cl = i - b*192;
    hsh[b][cl] = fmaxf(hpre[b*768 + c0 + cl], 0.f);
  }
  __syncthreads();
  int ow = t & 31, bi = t >> 5;
  int o = n0 + ow;
  if (o >= NCn) return;
  const float* w = W2 + (size_t)c0*NCn + o;
  float pacc[16];
  #pragma unroll
  for (int i = 0; i < 16; ++i) pacc[i] = 0.f;
  for (int cl = 0; cl < 192; cl += 16){
    #pragma unroll
    for (int i = 0; i < 16; ++i)
      pacc[i] = fmaf(hsh[bi][cl + i], w[(size_t)(cl + i)*NCn], pacc[i]);
  }
  float acc = ((pacc[0]+pacc[1])+(pacc[2]+pacc[3])) + ((pacc[4]+pacc[5])+(pacc[6]+pacc[7]))
            + ((pacc[8]+pacc[9])+(pacc[10]+pacc[11])) + ((pacc[12]+pacc[13])+(pacc[14]+pacc[15]));
  if (kc == 0) acc += b2[o];
  atomicAdd(&out[bi*NCn + o], acc);
}

extern "C" void kernel_launch(void* const* d_in, const int* in_sizes, int n_in,
                              void* d_out, int out_size, void* d_ws, size_t ws_size,
                              hipStream_t stream){
  const float* pl = (const float*)d_in[0];
  const float* hs = (const float*)d_in[2];
  const float* feat[4]; const float* pos[4]; const void* mask[4];
  const float* cw[4]; const float* cb[4]; const float* lg[4]; const float* lb[4];
  for (int s = 0; s < 4; ++s){
    int base = 3 + 7*s;
    feat[s] = (const float*)d_in[base];
    pos[s]  = (const float*)d_in[base+1];
    mask[s] = d_in[base+2];
    cw[s]   = (const float*)d_in[base+3];
    cb[s]   = (const float*)d_in[base+4];
    lg[s]   = (const float*)d_in[base+5];
    lb[s]   = (const float*)d_in[base+6];
  }
  const float* lq  = (const float*)d_in[31];
  const float* Wq  = (const float*)d_in[32];
  const float* bq  = (const float*)d_in[33];
  const float* qng = (const float*)d_in[34];
  const float* qnb = (const float*)d_in[35];
  const float* W1  = (const float*)d_in[36];
  const float* b1  = (const float*)d_in[37];
  const float* W2  = (const float*)d_in[38];
  const float* b2  = (const float*)d_in[39];
  float* out = (float*)d_out;

  // ---- workspace layout (~1.7 MB)
  short* Wswz   = (short*)d_ws;                        // [4][8][4][768][8] bf16 = 1.5 MB
  float* pooled = (float*)(Wswz + (size_t)4*8*4*768*8);// 40*256
  float* qt     = pooled + 40*RSn;                     // 8*6*768
  float* ctxsum = qt + Bn*6*QSn;                       // 8*768 (zeroed by k_front)
  float* hpre   = ctxsum + Bn*QSn;                     // 8*768 (zeroed by k_front)
  int*   det    = (int*)(hpre + Bn*QSn);               // 2 ints
  int*   flags  = det + 4;                             // 40 ints

  k_front<<<825, 256, 0, stream>>>(cw[0], cw[1], cw[2], cw[3], Wswz,
                                   (const int*)mask[0], det, pl, hs, pooled, flags,
                                   ctxsum, out);
  k_pgemm<<<728, 256, 0, stream>>>(feat[0], pos[0], mask[0],
                                   feat[1], pos[1], mask[1],
                                   feat[2], pos[2], mask[2],
                                   feat[3], pos[3], mask[3],
                                   det, Wswz,
                                   cb[0], cb[1], cb[2], cb[3],
                                   lg[0], lb[0], lg[1], lb[1],
                                   lg[2], lb[2], lg[3], lb[3], ctxsum,
                                   lq, Wq, bq, qng, qnb, pooled, flags, qt);
  k_hpre<<<96, 256, 0, stream>>>(qt, ctxsum, W1, b1, hpre);
  k_out<<<52, 256, 0, stream>>>(hpre, W2, b2, out);
}

// Round 11
// 241.320 us; speedup vs baseline: 1.3369x; 1.3369x over previous
//
#include <hip/hip_runtime.h>
#include <hip/hip_bf16.h>

#define Bn 8
#define Qn 300
#define Pn 5
#define RSn 256
#define QSn 768
#define NCn 396
#define MTOT 10880
#define THRL -1.3862943611198906f   // log(0.2/0.8): sigmoid(x)>0.2 <=> x>THRL

typedef __attribute__((ext_vector_type(8))) short short8;
typedef __attribute__((ext_vector_type(4))) float float4v;

__device__ inline float wred(float v){
  #pragma unroll
  for (int off = 32; off; off >>= 1) v += __shfl_xor(v, off);
  return v;
}

__device__ __forceinline__ unsigned short f2bf(float f){
  union { float f; unsigned int u; } c; c.f = f;
  return (unsigned short)((c.u + 0x7FFF + ((c.u >> 16) & 1)) >> 16);   // RNE
}

// =====================================================================
// D1: k_front — block roles REORDERED so the long-chain query-pooling
// blocks launch first (they are the makespan tail):
//   [0,40): query pooling (round-8 proven 12-chain ILP form)
//   [40,808): convW f32 -> bf16 swizzled Wswz[s][kc][lk][n][8]
//   808: mask detect ; [809,821): zero ctxsum+hpre ; [821,825): zero out
// =====================================================================
__global__ __launch_bounds__(256, 4) void k_front(
    const float* cw0, const float* cw1, const float* cw2, const float* cw3,
    short* Wswz, const int* __restrict__ mk0, int* det,
    const float* __restrict__ pl, const float* __restrict__ hs,
    float* pooled, int* flags, float* ctxsum, float* outz){
  int bx = blockIdx.x;
  int t = threadIdx.x;
  if (bx < 40){
    // ---- query pooling: 12 independent accumulator chains (300 = 25x12)
    __shared__ float msk[Qn];
    int bb = bx / Pn, p = bx % Pn;
    for (int q = t; q < Qn; q += 256)
      msk[q] = (pl[(bb*Qn + q)*Pn + p] > THRL) ? 1.f : 0.f;
    __syncthreads();
    const float* hb = hs + (size_t)bb*Qn*RSn + t;
    float sA[12];
    #pragma unroll
    for (int i = 0; i < 12; ++i) sA[i] = 0.f;
    float cnt = 0.f;
    for (int q0 = 0; q0 < Qn; q0 += 12){
      #pragma unroll
      for (int i = 0; i < 12; ++i){
        float m = msk[q0 + i];
        cnt += m;
        sA[i] = fmaf(m, hb[(size_t)(q0 + i)*RSn], sA[i]);
      }
    }
    float ssum = ((sA[0]+sA[1]) + (sA[2]+sA[3])) + ((sA[4]+sA[5]) + (sA[6]+sA[7]))
               + ((sA[8]+sA[9]) + (sA[10]+sA[11]));
    pooled[(bb*Pn + p)*RSn + t] = (cnt > 0.f) ? ssum / cnt : 0.f;
    if (t == 0) flags[bb*Pn + p] = (cnt > 0.f) ? 1 : 0;
    return;
  }
  if (bx < 808){
    int cbx = bx - 40;
    int s = cbx / 192;
    int linear = (cbx % 192)*256 + t;
    int q = linear & 63, n = linear >> 6;
    const float* src = (s==0)?cw0:(s==1)?cw1:(s==2)?cw2:cw3;
    float4 f = *(const float4*)(src + (size_t)n*256 + q*4);
    int kc = q >> 3, lk = (q >> 1) & 3, e0 = (q & 1)*4;
    short* dst = Wswz + ((size_t)(s*8 + kc))*24576 + lk*6144 + n*8 + e0;
    short4 sv;
    sv.x = (short)f2bf(f.x); sv.y = (short)f2bf(f.y);
    sv.z = (short)f2bf(f.z); sv.w = (short)f2bf(f.w);
    *(short4*)dst = sv;
    return;
  }
  if (bx == 808){
    __shared__ int r0[4], r1[4];
    const int* mm = mk0 + t*32;
    int d0 = 0, d1 = 0;
    #pragma unroll 8
    for (int i = 0; i < 32; ++i){
      int v = mm[i];
      d0 |= (v != 0 && v != 1);
      d1 |= (v != 0 && v != 0x3F800000);
    }
    unsigned long long bal0 = __ballot(d0), bal1 = __ballot(d1);
    int wid = t >> 6;
    if ((t & 63) == 0){ r0[wid] = (bal0 != 0ull); r1[wid] = (bal1 != 0ull); }
    __syncthreads();
    if (t == 0){
      det[0] = r0[0] | r0[1] | r0[2] | r0[3];
      det[1] = r1[0] | r1[1] | r1[2] | r1[3];
    }
    return;
  }
  if (bx >= 821){
    int idx = ((bx - 821)*256 + t)*4;
    if (idx < Bn*NCn) *(float4*)(outz + idx) = (float4){0.f,0.f,0.f,0.f};
    return;
  }
  // bx in [809,821): zero ctxsum(6144)+hpre(6144)
  {
    int idx = ((bx - 809)*256 + t)*4;
    *(float4*)(ctxsum + idx) = (float4){0.f,0.f,0.f,0.f};
  }
}

// =====================================================================
// D2: k_pgemm — blocks [0,680): fused pool + MFMA GEMM + bias + LN + token-sum
//               blocks [680,728): query tokens + LN -> qt
// (exact round-8 source — best measured config, 242.2 us)
// =====================================================================
__global__ __launch_bounds__(256, 3) void k_pgemm(
    const float* fe0, const float* po0, const void* ma0,
    const float* fe1, const float* po1, const void* ma1,
    const float* fe2, const float* po2, const void* ma2,
    const float* fe3, const float* po3, const void* ma3,
    const int* __restrict__ det, const short* __restrict__ Wswz,
    const float* cb0, const float* cb1, const float* cb2, const float* cb3,
    const float* lg0, const float* lb0, const float* lg1, const float* lb1,
    const float* lg2, const float* lb2, const float* lg3, const float* lb3,
    float* __restrict__ ctxsum,
    const float* __restrict__ lq, const float* __restrict__ Wq,
    const float* __restrict__ bq, const float* __restrict__ qng,
    const float* __restrict__ qnb, const float* __restrict__ pooled,
    const int* __restrict__ flags, float* qt){
  __shared__ short As[16*264];        // 8.25 KB A-tile [m][k], pitch 264
  __shared__ float wls[16][4];
  __shared__ float scls[16], imls[16];
  __shared__ float lsum[4][16], lsq[4][16];
  __shared__ float pq[256];
  __shared__ float s1s[4], s2s[4];
  int blk = blockIdx.x;
  int t = threadIdx.x;

  if (blk >= 680){
    // ---- query tokens + LN
    int qbx = blk - 680;
    int b = qbx / 6, j = qbx % 6;
    float v0 = lq[j*QSn + t], v1 = lq[j*QSn + t + 256], v2 = lq[j*QSn + t + 512];
    int any = flags[b*Pn] | flags[b*Pn+1] | flags[b*Pn+2] | flags[b*Pn+3] | flags[b*Pn+4];
    if (j > 0 && any){
      pq[t] = pooled[(b*Pn + (j-1))*RSn + t];
      __syncthreads();
      float a0 = 0.f, a1 = 0.f, a2 = 0.f;
      #pragma unroll 8
      for (int c = 0; c < RSn; ++c){
        float pv = pq[c];
        a0 = fmaf(pv, Wq[c*QSn + t      ], a0);
        a1 = fmaf(pv, Wq[c*QSn + t + 256], a1);
        a2 = fmaf(pv, Wq[c*QSn + t + 512], a2);
      }
      v0 += a0 + bq[t]; v1 += a1 + bq[t+256]; v2 += a2 + bq[t+512];
    }
    float sm = v0 + v1 + v2, sq = v0*v0 + v1*v1 + v2*v2;
    sm = wred(sm); sq = wred(sq);
    int wid = t >> 6, lane = t & 63;
    if (lane == 0){ s1s[wid] = sm; s2s[wid] = sq; }
    __syncthreads();
    float S  = s1s[0] + s1s[1] + s1s[2] + s1s[3];
    float SQ = s2s[0] + s2s[1] + s2s[2] + s2s[3];
    float mu = S * (1.f/QSn), var = SQ * (1.f/QSn) - mu*mu;
    float rs = rsqrtf(var + 1e-5f);
    float* o = qt + (b*6 + j)*QSn;
    o[t      ] = (v0 - mu)*rs*qng[t      ] + qnb[t      ];
    o[t + 256] = (v1 - mu)*rs*qng[t + 256] + qnb[t + 256];
    o[t + 512] = (v2 - mu)*rs*qng[t + 512] + qnb[t + 512];
    return;
  }

  int m0 = blk * 16;
  int s, H, OWlog, b0;
  const float *F, *Pp; const void* M;
  const float *CB, *LG, *LB;
  if (m0 < 8192){ s=0; F=fe0; Pp=po0; M=ma0; H=64; OWlog=5; b0=m0>>10;
                  CB=cb0; LG=lg0; LB=lb0; }
  else if (m0 < 10240){ s=1; F=fe1; Pp=po1; M=ma1; H=32; OWlog=4; b0=(m0-8192)>>8;
                  CB=cb1; LG=lg1; LB=lb1; }
  else if (m0 < 10752){ s=2; F=fe2; Pp=po2; M=ma2; H=16; OWlog=3; b0=(m0-10240)>>6;
                  CB=cb2; LG=lg2; LB=lb2; }
  else { s=3; F=fe3; Pp=po3; M=ma3; H=8; OWlog=2; b0=(m0-10752)>>4;
                  CB=cb3; LG=lg3; LB=lb3; }
  int HH = H*H;
  int OWm = (H >> 1) - 1;
  int mode = (det[0] == 0) ? 0 : ((det[1] == 0) ? 2 : 1);

  // per-slot token geometry (slot = t&15; blocks never cross batch images)
  int slot = t & 15;
  int gm = m0 + slot;
  int bb = b0;
  int ltl;
  if (s == 0)      ltl = gm & 1023;
  else if (s == 1) ltl = gm & 255;
  else if (s == 2) ltl = gm & 63;
  else             ltl = gm & 15;
  int ph = ltl >> OWlog, pw = ltl & OWm;
  int i00 = ph*2*H + pw*2;
  int mbase = bb*HH;

  // ---- step 1: mask weights per token (threads 0..15)
  if (t < 16){
    float w0, w1, w2, w3;
    if (mode == 0){
      const int* Mi = (const int*)M + mbase + i00;
      int2 ma = *(const int2*)(Mi);
      int2 mb = *(const int2*)(Mi + H);
      w0 = ma.x?0.f:1.f; w1 = ma.y?0.f:1.f; w2 = mb.x?0.f:1.f; w3 = mb.y?0.f:1.f;
    } else if (mode == 1){
      const unsigned char* Mb = (const unsigned char*)M + mbase + i00;
      w0 = Mb[0]?0.f:1.f; w1 = Mb[1]?0.f:1.f; w2 = Mb[H]?0.f:1.f; w3 = Mb[H+1]?0.f:1.f;
    } else {
      const float* Mf = (const float*)M + mbase + i00;
      float2 ma = *(const float2*)(Mf);
      float2 mb = *(const float2*)(Mf + H);
      w0 = 1.f-ma.x; w1 = 1.f-ma.y; w2 = 1.f-mb.x; w3 = 1.f-mb.y;
    }
    float msum = w0 + w1 + w2 + w3;
    float im = 1.f / fmaxf(msum*0.25f, 1e-6f);
    wls[t][0] = w0; wls[t][1] = w1; wls[t][2] = w2; wls[t][3] = w3;
    scls[t] = 0.25f*im; imls[t] = im;
  }
  __syncthreads();

  // ---- step 2: pool 256 channels into As[m][k]; 2 ch/thread/round, 8 rounds
  {
    float w0 = wls[slot][0], w1 = wls[slot][1], w2 = wls[slot][2], w3 = wls[slot][3];
    float sc = scls[slot];
    int chb = (t >> 4) * 2;                 // 0..30
    size_t base = (size_t)(bb*256 + chb)*HH + i00;
    const float* Fp = F + base;
    const float* Pq = Pp + base;
    const int stride = 32*HH;
    #pragma unroll 2
    for (int r = 0; r < 8; ++r){
      float2 fa0 = *(const float2*)(Fp);
      float2 fb0 = *(const float2*)(Fp + H);
      float2 pa0 = *(const float2*)(Pq);
      float2 pb0 = *(const float2*)(Pq + H);
      float2 fa1 = *(const float2*)(Fp + HH);
      float2 fb1 = *(const float2*)(Fp + HH + H);
      float2 pa1 = *(const float2*)(Pq + HH);
      float2 pb1 = *(const float2*)(Pq + HH + H);
      float x0 = (fa0.x+pa0.x)*w0 + (fa0.y+pa0.y)*w1 + (fb0.x+pb0.x)*w2 + (fb0.y+pb0.y)*w3;
      float x1 = (fa1.x+pa1.x)*w0 + (fa1.y+pa1.y)*w1 + (fb1.x+pb1.x)*w2 + (fb1.y+pb1.y)*w3;
      *(unsigned int*)(&As[slot*264 + chb + r*32]) =
          (unsigned int)f2bf(x0*sc) | ((unsigned int)f2bf(x1*sc) << 16);
      Fp += stride; Pq += stride;
    }
  }
  __syncthreads();

  // ---- A fragments to registers
  int wid = t >> 6, l = t & 63;
  int lm = l & 15, lk = l >> 4;
  int nfb = wid * 12;
  short8 aReg[8];
  #pragma unroll
  for (int kc = 0; kc < 8; ++kc)
    aReg[kc] = *(const short8*)(As + lm*264 + kc*32 + lk*8);

  float4v acc[12];
  #pragma unroll
  for (int nf = 0; nf < 12; ++nf) acc[nf] = (float4v){0.f,0.f,0.f,0.f};

  // ---- K loop: B fragments straight from L2 (pre-swizzled, 16B/lane)
  const short* Bb = Wswz + ((size_t)(s*8))*24576 + lk*6144 + nfb*128 + lm*8;
  #pragma unroll
  for (int kc = 0; kc < 8; ++kc){
    const short* bp = Bb + kc*24576;
    #pragma unroll
    for (int nf = 0; nf < 12; ++nf){
      short8 bf = *(const short8*)(bp + nf*128);
      acc[nf] = __builtin_amdgcn_mfma_f32_16x16x32_bf16(aReg[kc], bf, acc[nf], 0, 0, 0);
    }
  }

  // ---- epilogue: bias (via LDS im), per-row LN, token-sum -> ctxsum
  float im4[4];
  #pragma unroll
  for (int r = 0; r < 4; ++r) im4[r] = imls[lk*4 + r];

  float sum[4] = {0,0,0,0}, sq[4] = {0,0,0,0};
  #pragma unroll
  for (int nf = 0; nf < 12; ++nf){
    float cbv = CB[(nfb+nf)*16 + lm];
    #pragma unroll
    for (int r = 0; r < 4; ++r){
      float p = acc[nf][r] + cbv*im4[r];
      acc[nf][r] = p;
      sum[r] += p;
      sq[r] = fmaf(p, p, sq[r]);
    }
  }
  #pragma unroll
  for (int r = 0; r < 4; ++r){
    #pragma unroll
    for (int off = 1; off < 16; off <<= 1){
      sum[r] += __shfl_xor(sum[r], off);
      sq[r]  += __shfl_xor(sq[r],  off);
    }
  }
  if (lm == 0){
    #pragma unroll
    for (int r = 0; r < 4; ++r){
      lsum[wid][lk*4 + r] = sum[r];
      lsq[wid][lk*4 + r]  = sq[r];
    }
  }
  __syncthreads();
  float mu[4], rs[4];
  #pragma unroll
  for (int r = 0; r < 4; ++r){
    int row = lk*4 + r;
    float S  = lsum[0][row] + lsum[1][row] + lsum[2][row] + lsum[3][row];
    float SQ = lsq[0][row]  + lsq[1][row]  + lsq[2][row]  + lsq[3][row];
    mu[r] = S * (1.f/768.f);
    float var = SQ * (1.f/768.f) - mu[r]*mu[r];
    rs[r] = rsqrtf(var + 1e-5f);
  }
  #pragma unroll
  for (int nf = 0; nf < 12; ++nf){
    int n = (nfb+nf)*16 + lm;
    float g = LG[n], bv = LB[n];
    float tv = 0.f;
    #pragma unroll
    for (int r = 0; r < 4; ++r)
      tv += (acc[nf][r] - mu[r]) * rs[r];
    tv = tv*g + 4.f*bv;
    tv += __shfl_xor(tv, 16); tv += __shfl_xor(tv, 32);
    if (lk == 0)
      atomicAdd(&ctxsum[b0*768 + n], tv);
  }
}

// =====================================================================
// D3: k_hpre — hpre += v @ W1 (+b1). Grid 96 = 24n(32col) x 4k(192c).
// 16 partial accumulators (round-8 ILP win).
// =====================================================================
__global__ void k_hpre(const float* __restrict__ qt, const float* __restrict__ ctxsum,
                       const float* __restrict__ W1, const float* __restrict__ b1,
                       float* __restrict__ hpre){
  __shared__ float vsh[Bn][192];
  int nc = blockIdx.x % 24, kc = blockIdx.x / 24;
  int n0 = nc*32, c0 = kc*192;
  int t = threadIdx.x;
  for (int i = t; i < Bn*192; i += 256){
    int b = i / 192, cl = i - b*192;
    int c = c0 + cl;
    const float* q = qt + (size_t)b*6*768;
    float pm = q[768+c] + q[2*768+c] + q[3*768+c] + q[4*768+c] + q[5*768+c];
    vsh[b][cl] = q[c] + 0.2f*pm + ctxsum[b*768 + c]*(1.f/680.f);
  }
  __syncthreads();
  int ow = t & 31, bi = t >> 5;
  int o = n0 + ow;
  const float* w = W1 + (size_t)c0*768 + o;
  float pacc[16];
  #pragma unroll
  for (int i = 0; i < 16; ++i) pacc[i] = 0.f;
  for (int cl = 0; cl < 192; cl += 16){
    #pragma unroll
    for (int i = 0; i < 16; ++i)
      pacc[i] = fmaf(vsh[bi][cl + i], w[(size_t)(cl + i)*768], pacc[i]);
  }
  float acc = ((pacc[0]+pacc[1])+(pacc[2]+pacc[3])) + ((pacc[4]+pacc[5])+(pacc[6]+pacc[7]))
            + ((pacc[8]+pacc[9])+(pacc[10]+pacc[11])) + ((pacc[12]+pacc[13])+(pacc[14]+pacc[15]));
  if (kc == 0) acc += b1[o];
  atomicAdd(&hpre[bi*768 + o], acc);
}

// =====================================================================
// D4: k_out — out += relu(hpre) @ W2 (+b2). Grid 52 = 13n(32) x 4k(192).
// =====================================================================
__global__ void k_out(const float* __restrict__ hpre, const float* __restrict__ W2,
                      const float* __restrict__ b2, float* __restrict__ out){
  __shared__ float hsh[Bn][192];
  int nc = blockIdx.x % 13, kc = blockIdx.x / 13;
  int n0 = nc*32, c0 = kc*192;
  int t = threadIdx.x;
  for (int i = t; i < Bn*192; i += 256){
    int b = i / 192, cl = i - b*192;
    hsh[b][cl] = fmaxf(hpre[b*768 + c0 + cl], 0.f);
  }
  __syncthreads();
  int ow = t & 31, bi = t >> 5;
  int o = n0 + ow;
  if (o >= NCn) return;
  const float* w = W2 + (size_t)c0*NCn + o;
  float pacc[16];
  #pragma unroll
  for (int i = 0; i < 16; ++i) pacc[i] = 0.f;
  for (int cl = 0; cl < 192; cl += 16){
    #pragma unroll
    for (int i = 0; i < 16; ++i)
      pacc[i] = fmaf(hsh[bi][cl + i], w[(size_t)(cl + i)*NCn], pacc[i]);
  }
  float acc = ((pacc[0]+pacc[1])+(pacc[2]+pacc[3])) + ((pacc[4]+pacc[5])+(pacc[6]+pacc[7]))
            + ((pacc[8]+pacc[9])+(pacc[10]+pacc[11])) + ((pacc[12]+pacc[13])+(pacc[14]+pacc[15]));
  if (kc == 0) acc += b2[o];
  atomicAdd(&out[bi*NCn + o], acc);
}

extern "C" void kernel_launch(void* const* d_in, const int* in_sizes, int n_in,
                              void* d_out, int out_size, void* d_ws, size_t ws_size,
                              hipStream_t stream){
  const float* pl = (const float*)d_in[0];
  const float* hs = (const float*)d_in[2];
  const float* feat[4]; const float* pos[4]; const void* mask[4];
  const float* cw[4]; const float* cb[4]; const float* lg[4]; const float* lb[4];
  for (int s = 0; s < 4; ++s){
    int base = 3 + 7*s;
    feat[s] = (const float*)d_in[base];
    pos[s]  = (const float*)d_in[base+1];
    mask[s] = d_in[base+2];
    cw[s]   = (const float*)d_in[base+3];
    cb[s]   = (const float*)d_in[base+4];
    lg[s]   = (const float*)d_in[base+5];
    lb[s]   = (const float*)d_in[base+6];
  }
  const float* lq  = (const float*)d_in[31];
  const float* Wq  = (const float*)d_in[32];
  const float* bq  = (const float*)d_in[33];
  const float* qng = (const float*)d_in[34];
  const float* qnb = (const float*)d_in[35];
  const float* W1  = (const float*)d_in[36];
  const float* b1  = (const float*)d_in[37];
  const float* W2  = (const float*)d_in[38];
  const float* b2  = (const float*)d_in[39];
  float* out = (float*)d_out;

  // ---- workspace layout (~1.7 MB)
  short* Wswz   = (short*)d_ws;                        // [4][8][4][768][8] bf16 = 1.5 MB
  float* pooled = (float*)(Wswz + (size_t)4*8*4*768*8);// 40*256
  float* qt     = pooled + 40*RSn;                     // 8*6*768
  float* ctxsum = qt + Bn*6*QSn;                       // 8*768 (zeroed by k_front)
  float* hpre   = ctxsum + Bn*QSn;                     // 8*768 (zeroed by k_front)
  int*   det    = (int*)(hpre + Bn*QSn);               // 2 ints
  int*   flags  = det + 4;                             // 40 ints

  k_front<<<825, 256, 0, stream>>>(cw[0], cw[1], cw[2], cw[3], Wswz,
                                   (const int*)mask[0], det, pl, hs, pooled, flags,
                                   ctxsum, out);
  k_pgemm<<<728, 256, 0, stream>>>(feat[0], pos[0], mask[0],
                                   feat[1], pos[1], mask[1],
                                   feat[2], pos[2], mask[2],
                                   feat[3], pos[3], mask[3],
                                   det, Wswz,
                                   cb[0], cb[1], cb[2], cb[3],
                                   lg[0], lb[0], lg[1], lb[1],
                                   lg[2], lb[2], lg[3], lb[3], ctxsum,
                                   lq, Wq, bq, qng, qnb, pooled, flags, qt);
  k_hpre<<<96, 256, 0, stream>>>(qt, ctxsum, W1, b1, hpre);
  k_out<<<52, 256, 0, stream>>>(hpre, W2, b2, out);
}

// Round 12
// 239.882 us; speedup vs baseline: 1.3449x; 1.0060x over previous
//
#include <hip/hip_runtime.h>
#include <hip/hip_bf16.h>

#define Bn 8
#define Qn 300
#define Pn 5
#define RSn 256
#define QSn 768
#define NCn 396
#define MTOT 10880
#define THRL -1.3862943611198906f   // log(0.2/0.8): sigmoid(x)>0.2 <=> x>THRL

typedef __attribute__((ext_vector_type(8))) short short8;
typedef __attribute__((ext_vector_type(4))) float float4v;

__device__ inline float wred(float v){
  #pragma unroll
  for (int off = 32; off; off >>= 1) v += __shfl_xor(v, off);
  return v;
}

__device__ __forceinline__ unsigned short f2bf(float f){
  union { float f; unsigned int u; } c; c.f = f;
  return (unsigned short)((c.u + 0x7FFF + ((c.u >> 16) & 1)) >> 16);   // RNE
}

// =====================================================================
// D1: k_front — [0,40): query pooling first (long-chain tail);
//   [40,808): convW f32 -> bf16 swizzled Wswz; 808: mask detect;
//   [809,821): zero ctxsum+hpre ; [821,825): zero out
// (exact round-11 source — 241.3 us base)
// =====================================================================
__global__ __launch_bounds__(256, 4) void k_front(
    const float* cw0, const float* cw1, const float* cw2, const float* cw3,
    short* Wswz, const int* __restrict__ mk0, int* det,
    const float* __restrict__ pl, const float* __restrict__ hs,
    float* pooled, int* flags, float* ctxsum, float* outz){
  int bx = blockIdx.x;
  int t = threadIdx.x;
  if (bx < 40){
    // ---- query pooling: 12 independent accumulator chains (300 = 25x12)
    __shared__ float msk[Qn];
    int bb = bx / Pn, p = bx % Pn;
    for (int q = t; q < Qn; q += 256)
      msk[q] = (pl[(bb*Qn + q)*Pn + p] > THRL) ? 1.f : 0.f;
    __syncthreads();
    const float* hb = hs + (size_t)bb*Qn*RSn + t;
    float sA[12];
    #pragma unroll
    for (int i = 0; i < 12; ++i) sA[i] = 0.f;
    float cnt = 0.f;
    for (int q0 = 0; q0 < Qn; q0 += 12){
      #pragma unroll
      for (int i = 0; i < 12; ++i){
        float m = msk[q0 + i];
        cnt += m;
        sA[i] = fmaf(m, hb[(size_t)(q0 + i)*RSn], sA[i]);
      }
    }
    float ssum = ((sA[0]+sA[1]) + (sA[2]+sA[3])) + ((sA[4]+sA[5]) + (sA[6]+sA[7]))
               + ((sA[8]+sA[9]) + (sA[10]+sA[11]));
    pooled[(bb*Pn + p)*RSn + t] = (cnt > 0.f) ? ssum / cnt : 0.f;
    if (t == 0) flags[bb*Pn + p] = (cnt > 0.f) ? 1 : 0;
    return;
  }
  if (bx < 808){
    int cbx = bx - 40;
    int s = cbx / 192;
    int linear = (cbx % 192)*256 + t;
    int q = linear & 63, n = linear >> 6;
    const float* src = (s==0)?cw0:(s==1)?cw1:(s==2)?cw2:cw3;
    float4 f = *(const float4*)(src + (size_t)n*256 + q*4);
    int kc = q >> 3, lk = (q >> 1) & 3, e0 = (q & 1)*4;
    short* dst = Wswz + ((size_t)(s*8 + kc))*24576 + lk*6144 + n*8 + e0;
    short4 sv;
    sv.x = (short)f2bf(f.x); sv.y = (short)f2bf(f.y);
    sv.z = (short)f2bf(f.z); sv.w = (short)f2bf(f.w);
    *(short4*)dst = sv;
    return;
  }
  if (bx == 808){
    __shared__ int r0[4], r1[4];
    const int* mm = mk0 + t*32;
    int d0 = 0, d1 = 0;
    #pragma unroll 8
    for (int i = 0; i < 32; ++i){
      int v = mm[i];
      d0 |= (v != 0 && v != 1);
      d1 |= (v != 0 && v != 0x3F800000);
    }
    unsigned long long bal0 = __ballot(d0), bal1 = __ballot(d1);
    int wid = t >> 6;
    if ((t & 63) == 0){ r0[wid] = (bal0 != 0ull); r1[wid] = (bal1 != 0ull); }
    __syncthreads();
    if (t == 0){
      det[0] = r0[0] | r0[1] | r0[2] | r0[3];
      det[1] = r1[0] | r1[1] | r1[2] | r1[3];
    }
    return;
  }
  if (bx >= 821){
    int idx = ((bx - 821)*256 + t)*4;
    if (idx < Bn*NCn) *(float4*)(outz + idx) = (float4){0.f,0.f,0.f,0.f};
    return;
  }
  // bx in [809,821): zero ctxsum(6144)+hpre(6144)
  {
    int idx = ((bx - 809)*256 + t)*4;
    *(float4*)(ctxsum + idx) = (float4){0.f,0.f,0.f,0.f};
  }
}

// =====================================================================
// D2: k_pgemm — blocks [0,680): fused pool + MFMA GEMM + bias + LN + token-sum
//               blocks [680,728): query tokens + LN -> qt
// Round-12: round-11 base with ONE change — pool phase uses the round-10
// verified-correct token-pair float4 addressing (32x16B loads/thread,
// fully unrolled; per-thread mask weights; first barrier gone). Doubles
// in-flight pool bytes per wave (Little's law: 3KB/CU was the limiter).
// =====================================================================
__global__ __launch_bounds__(256, 3) void k_pgemm(
    const float* fe0, const float* po0, const void* ma0,
    const float* fe1, const float* po1, const void* ma1,
    const float* fe2, const float* po2, const void* ma2,
    const float* fe3, const float* po3, const void* ma3,
    const int* __restrict__ det, const short* __restrict__ Wswz,
    const float* cb0, const float* cb1, const float* cb2, const float* cb3,
    const float* lg0, const float* lb0, const float* lg1, const float* lb1,
    const float* lg2, const float* lb2, const float* lg3, const float* lb3,
    float* __restrict__ ctxsum,
    const float* __restrict__ lq, const float* __restrict__ Wq,
    const float* __restrict__ bq, const float* __restrict__ qng,
    const float* __restrict__ qnb, const float* __restrict__ pooled,
    const int* __restrict__ flags, float* qt){
  __shared__ short As[16*264];        // 8.25 KB A-tile [m][k], pitch 264
  __shared__ float imls[16];
  __shared__ float lsum[4][16], lsq[4][16];
  __shared__ float pq[256];
  __shared__ float s1s[4], s2s[4];
  int blk = blockIdx.x;
  int t = threadIdx.x;

  if (blk >= 680){
    // ---- query tokens + LN
    int qbx = blk - 680;
    int b = qbx / 6, j = qbx % 6;
    float v0 = lq[j*QSn + t], v1 = lq[j*QSn + t + 256], v2 = lq[j*QSn + t + 512];
    int any = flags[b*Pn] | flags[b*Pn+1] | flags[b*Pn+2] | flags[b*Pn+3] | flags[b*Pn+4];
    if (j > 0 && any){
      pq[t] = pooled[(b*Pn + (j-1))*RSn + t];
      __syncthreads();
      float a0 = 0.f, a1 = 0.f, a2 = 0.f;
      #pragma unroll 8
      for (int c = 0; c < RSn; ++c){
        float pv = pq[c];
        a0 = fmaf(pv, Wq[c*QSn + t      ], a0);
        a1 = fmaf(pv, Wq[c*QSn + t + 256], a1);
        a2 = fmaf(pv, Wq[c*QSn + t + 512], a2);
      }
      v0 += a0 + bq[t]; v1 += a1 + bq[t+256]; v2 += a2 + bq[t+512];
    }
    float sm = v0 + v1 + v2, sq = v0*v0 + v1*v1 + v2*v2;
    sm = wred(sm); sq = wred(sq);
    int wid = t >> 6, lane = t & 63;
    if (lane == 0){ s1s[wid] = sm; s2s[wid] = sq; }
    __syncthreads();
    float S  = s1s[0] + s1s[1] + s1s[2] + s1s[3];
    float SQ = s2s[0] + s2s[1] + s2s[2] + s2s[3];
    float mu = S * (1.f/QSn), var = SQ * (1.f/QSn) - mu*mu;
    float rs = rsqrtf(var + 1e-5f);
    float* o = qt + (b*6 + j)*QSn;
    o[t      ] = (v0 - mu)*rs*qng[t      ] + qnb[t      ];
    o[t + 256] = (v1 - mu)*rs*qng[t + 256] + qnb[t + 256];
    o[t + 512] = (v2 - mu)*rs*qng[t + 512] + qnb[t + 512];
    return;
  }

  int m0 = blk * 16;
  int s, H, OWlog, b0;
  const float *F, *Pp; const void* M;
  const float *CB, *LG, *LB;
  if (m0 < 8192){ s=0; F=fe0; Pp=po0; M=ma0; H=64; OWlog=5; b0=m0>>10;
                  CB=cb0; LG=lg0; LB=lb0; }
  else if (m0 < 10240){ s=1; F=fe1; Pp=po1; M=ma1; H=32; OWlog=4; b0=(m0-8192)>>8;
                  CB=cb1; LG=lg1; LB=lb1; }
  else if (m0 < 10752){ s=2; F=fe2; Pp=po2; M=ma2; H=16; OWlog=3; b0=(m0-10240)>>6;
                  CB=cb2; LG=lg2; LB=lb2; }
  else { s=3; F=fe3; Pp=po3; M=ma3; H=8; OWlog=2; b0=(m0-10752)>>4;
                  CB=cb3; LG=lg3; LB=lb3; }
  int HH = H*H;
  int OWm = (H >> 1) - 1;
  int mode = (det[0] == 0) ? 0 : ((det[1] == 0) ? 2 : 1);

  // ---- token-pair geometry: slotp = t&7 (8 pairs), cg = t>>3 (0..31)
  int slotp = t & 7;
  int cg = t >> 3;
  int mA = m0 + slotp*2;
  int ltl;
  if (s == 0)      ltl = mA & 1023;
  else if (s == 1) ltl = mA & 255;
  else if (s == 2) ltl = mA & 63;
  else             ltl = mA & 15;
  int ph = ltl >> OWlog, pw = ltl & OWm;   // pw even
  int i00 = ph*2*H + pw*2;                 // multiple of 4 -> float4 aligned
  int mbase = b0*HH;

  // ---- mask weights for both tokens of the pair (16B-span reads)
  float w0A,w1A,w2A,w3A, w0B,w1B,w2B,w3B;
  if (mode == 0){
    const int* Mi = (const int*)M + mbase + i00;
    int4 ma = *(const int4*)(Mi);
    int4 mb = *(const int4*)(Mi + H);
    w0A = ma.x?0.f:1.f; w1A = ma.y?0.f:1.f; w2A = mb.x?0.f:1.f; w3A = mb.y?0.f:1.f;
    w0B = ma.z?0.f:1.f; w1B = ma.w?0.f:1.f; w2B = mb.z?0.f:1.f; w3B = mb.w?0.f:1.f;
  } else if (mode == 1){
    const unsigned char* Mb = (const unsigned char*)M + mbase + i00;
    uchar4 av = *(const uchar4*)(Mb);
    uchar4 bv = *(const uchar4*)(Mb + H);
    w0A = av.x?0.f:1.f; w1A = av.y?0.f:1.f; w2A = bv.x?0.f:1.f; w3A = bv.y?0.f:1.f;
    w0B = av.z?0.f:1.f; w1B = av.w?0.f:1.f; w2B = bv.z?0.f:1.f; w3B = bv.w?0.f:1.f;
  } else {
    const float* Mf = (const float*)M + mbase + i00;
    float4 ma = *(const float4*)(Mf);
    float4 mb = *(const float4*)(Mf + H);
    w0A = 1.f-ma.x; w1A = 1.f-ma.y; w2A = 1.f-mb.x; w3A = 1.f-mb.y;
    w0B = 1.f-ma.z; w1B = 1.f-ma.w; w2B = 1.f-mb.z; w3B = 1.f-mb.w;
  }
  float msA = w0A+w1A+w2A+w3A, msB = w0B+w1B+w2B+w3B;
  float imA = 1.f / fmaxf(msA*0.25f, 1e-6f);
  float imB = 1.f / fmaxf(msB*0.25f, 1e-6f);
  float scA = 0.25f*imA, scB = 0.25f*imB;
  if (t < 8){ imls[t*2] = imA; imls[t*2 + 1] = imB; }

  // ---- pool 256 channels into As[m][k]: 8 fully-unrolled rounds of
  // 4 float4 loads (token-pair: xA from .x/.y, xB from .z/.w)
  {
    size_t base = (size_t)(b0*256 + cg)*HH + i00;
    const float* Fp = F + base;
    const float* Pq2 = Pp + base;
    const size_t stride = (size_t)32*HH;
    int rowA = slotp*2*264, rowB = rowA + 264;
    #pragma unroll
    for (int r = 0; r < 8; ++r){
      float4 f0 = *(const float4*)(Fp);
      float4 f1 = *(const float4*)(Fp + H);
      float4 p0 = *(const float4*)(Pq2);
      float4 p1 = *(const float4*)(Pq2 + H);
      float xA = (f0.x+p0.x)*w0A + (f0.y+p0.y)*w1A + (f1.x+p1.x)*w2A + (f1.y+p1.y)*w3A;
      float xB = (f0.z+p0.z)*w0B + (f0.w+p0.w)*w1B + (f1.z+p1.z)*w2B + (f1.w+p1.w)*w3B;
      As[rowA + cg + r*32] = (short)f2bf(xA*scA);
      As[rowB + cg + r*32] = (short)f2bf(xB*scB);
      Fp += stride; Pq2 += stride;
    }
  }
  __syncthreads();

  // ---- A fragments to registers
  int wid = t >> 6, l = t & 63;
  int lm = l & 15, lk = l >> 4;
  int nfb = wid * 12;
  short8 aReg[8];
  #pragma unroll
  for (int kc = 0; kc < 8; ++kc)
    aReg[kc] = *(const short8*)(As + lm*264 + kc*32 + lk*8);

  float4v acc[12];
  #pragma unroll
  for (int nf = 0; nf < 12; ++nf) acc[nf] = (float4v){0.f,0.f,0.f,0.f};

  // ---- K loop: B fragments straight from L2 (pre-swizzled, 16B/lane)
  const short* Bb = Wswz + ((size_t)(s*8))*24576 + lk*6144 + nfb*128 + lm*8;
  #pragma unroll
  for (int kc = 0; kc < 8; ++kc){
    const short* bp = Bb + kc*24576;
    #pragma unroll
    for (int nf = 0; nf < 12; ++nf){
      short8 bf = *(const short8*)(bp + nf*128);
      acc[nf] = __builtin_amdgcn_mfma_f32_16x16x32_bf16(aReg[kc], bf, acc[nf], 0, 0, 0);
    }
  }

  // ---- epilogue: bias (via LDS im), per-row LN, token-sum -> ctxsum
  float im4[4];
  #pragma unroll
  for (int r = 0; r < 4; ++r) im4[r] = imls[lk*4 + r];

  float sum[4] = {0,0,0,0}, sq[4] = {0,0,0,0};
  #pragma unroll
  for (int nf = 0; nf < 12; ++nf){
    float cbv = CB[(nfb+nf)*16 + lm];
    #pragma unroll
    for (int r = 0; r < 4; ++r){
      float p = acc[nf][r] + cbv*im4[r];
      acc[nf][r] = p;
      sum[r] += p;
      sq[r] = fmaf(p, p, sq[r]);
    }
  }
  #pragma unroll
  for (int r = 0; r < 4; ++r){
    #pragma unroll
    for (int off = 1; off < 16; off <<= 1){
      sum[r] += __shfl_xor(sum[r], off);
      sq[r]  += __shfl_xor(sq[r],  off);
    }
  }
  if (lm == 0){
    #pragma unroll
    for (int r = 0; r < 4; ++r){
      lsum[wid][lk*4 + r] = sum[r];
      lsq[wid][lk*4 + r]  = sq[r];
    }
  }
  __syncthreads();
  float mu[4], rs[4];
  #pragma unroll
  for (int r = 0; r < 4; ++r){
    int row = lk*4 + r;
    float S  = lsum[0][row] + lsum[1][row] + lsum[2][row] + lsum[3][row];
    float SQ = lsq[0][row]  + lsq[1][row]  + lsq[2][row]  + lsq[3][row];
    mu[r] = S * (1.f/768.f);
    float var = SQ * (1.f/768.f) - mu[r]*mu[r];
    rs[r] = rsqrtf(var + 1e-5f);
  }
  #pragma unroll
  for (int nf = 0; nf < 12; ++nf){
    int n = (nfb+nf)*16 + lm;
    float g = LG[n], bv = LB[n];
    float tv = 0.f;
    #pragma unroll
    for (int r = 0; r < 4; ++r)
      tv += (acc[nf][r] - mu[r]) * rs[r];
    tv = tv*g + 4.f*bv;
    tv += __shfl_xor(tv, 16); tv += __shfl_xor(tv, 32);
    if (lk == 0)
      atomicAdd(&ctxsum[b0*768 + n], tv);
  }
}

// =====================================================================
// D3: k_hpre — hpre += v @ W1 (+b1). Grid 96 = 24n(32col) x 4k(192c).
// 16 partial accumulators (round-8 ILP win).
// =====================================================================
__global__ void k_hpre(const float* __restrict__ qt, const float* __restrict__ ctxsum,
                       const float* __restrict__ W1, const float* __restrict__ b1,
                       float* __restrict__ hpre){
  __shared__ float vsh[Bn][192];
  int nc = blockIdx.x % 24, kc = blockIdx.x / 24;
  int n0 = nc*32, c0 = kc*192;
  int t = threadIdx.x;
  for (int i = t; i < Bn*192; i += 256){
    int b = i / 192, cl = i - b*192;
    int c = c0 + cl;
    const float* q = qt + (size_t)b*6*768;
    float pm = q[768+c] + q[2*768+c] + q[3*768+c] + q[4*768+c] + q[5*768+c];
    vsh[b][cl] = q[c] + 0.2f*pm + ctxsum[b*768 + c]*(1.f/680.f);
  }
  __syncthreads();
  int ow = t & 31, bi = t >> 5;
  int o = n0 + ow;
  const float* w = W1 + (size_t)c0*768 + o;
  float pacc[16];
  #pragma unroll
  for (int i = 0; i < 16; ++i) pacc[i] = 0.f;
  for (int cl = 0; cl < 192; cl += 16){
    #pragma unroll
    for (int i = 0; i < 16; ++i)
      pacc[i] = fmaf(vsh[bi][cl + i], w[(size_t)(cl + i)*768], pacc[i]);
  }
  float acc = ((pacc[0]+pacc[1])+(pacc[2]+pacc[3])) + ((pacc[4]+pacc[5])+(pacc[6]+pacc[7]))
            + ((pacc[8]+pacc[9])+(pacc[10]+pacc[11])) + ((pacc[12]+pacc[13])+(pacc[14]+pacc[15]));
  if (kc == 0) acc += b1[o];
  atomicAdd(&hpre[bi*768 + o], acc);
}

// =====================================================================
// D4: k_out — out += relu(hpre) @ W2 (+b2). Grid 52 = 13n(32) x 4k(192).
// =====================================================================
__global__ void k_out(const float* __restrict__ hpre, const float* __restrict__ W2,
                      const float* __restrict__ b2, float* __restrict__ out){
  __shared__ float hsh[Bn][192];
  int nc = blockIdx.x % 13, kc = blockIdx.x / 13;
  int n0 = nc*32, c0 = kc*192;
  int t = threadIdx.x;
  for (int i = t; i < Bn*192; i += 256){
    int b = i / 192, cl = i - b*192;
    hsh[b][cl] = fmaxf(hpre[b*768 + c0 + cl], 0.f);
  }
  __syncthreads();
  int ow = t & 31, bi = t >> 5;
  int o = n0 + ow;
  if (o >= NCn) return;
  const float* w = W2 + (size_t)c0*NCn + o;
  float pacc[16];
  #pragma unroll
  for (int i = 0; i < 16; ++i) pacc[i] = 0.f;
  for (int cl = 0; cl < 192; cl += 16){
    #pragma unroll
    for (int i = 0; i < 16; ++i)
      pacc[i] = fmaf(hsh[bi][cl + i], w[(size_t)(cl + i)*NCn], pacc[i]);
  }
  float acc = ((pacc[0]+pacc[1])+(pacc[2]+pacc[3])) + ((pacc[4]+pacc[5])+(pacc[6]+pacc[7]))
            + ((pacc[8]+pacc[9])+(pacc[10]+pacc[11])) + ((pacc[12]+pacc[13])+(pacc[14]+pacc[15]));
  if (kc == 0) acc += b2[o];
  atomicAdd(&out[bi*NCn + o], acc);
}

extern "C" void kernel_launch(void* const* d_in, const int* in_sizes, int n_in,
                              void* d_out, int out_size, void* d_ws, size_t ws_size,
                              hipStream_t stream){
  const float* pl = (const float*)d_in[0];
  const float* hs = (const float*)d_in[2];
  const float* feat[4]; const float* pos[4]; const void* mask[4];
  const float* cw[4]; const float* cb[4]; const float* lg[4]; const float* lb[4];
  for (int s = 0; s < 4; ++s){
    int base = 3 + 7*s;
    feat[s] = (const float*)d_in[base];
    pos[s]  = (const float*)d_in[base+1];
    mask[s] = d_in[base+2];
    cw[s]   = (const float*)d_in[base+3];
    cb[s]   = (const float*)d_in[base+4];
    lg[s]   = (const float*)d_in[base+5];
    lb[s]   = (const float*)d_in[base+6];
  }
  const float* lq  = (const float*)d_in[31];
  const float* Wq  = (const float*)d_in[32];
  const float* bq  = (const float*)d_in[33];
  const float* qng = (const float*)d_in[34];
  const float* qnb = (const float*)d_in[35];
  const float* W1  = (const float*)d_in[36];
  const float* b1  = (const float*)d_in[37];
  const float* W2  = (const float*)d_in[38];
  const float* b2  = (const float*)d_in[39];
  float* out = (float*)d_out;

  // ---- workspace layout (~1.7 MB)
  short* Wswz   = (short*)d_ws;                        // [4][8][4][768][8] bf16 = 1.5 MB
  float* pooled = (float*)(Wswz + (size_t)4*8*4*768*8);// 40*256
  float* qt     = pooled + 40*RSn;                     // 8*6*768
  float* ctxsum = qt + Bn*6*QSn;                       // 8*768 (zeroed by k_front)
  float* hpre   = ctxsum + Bn*QSn;                     // 8*768 (zeroed by k_front)
  int*   det    = (int*)(hpre + Bn*QSn);               // 2 ints
  int*   flags  = det + 4;                             // 40 ints

  k_front<<<825, 256, 0, stream>>>(cw[0], cw[1], cw[2], cw[3], Wswz,
                                   (const int*)mask[0], det, pl, hs, pooled, flags,
                                   ctxsum, out);
  k_pgemm<<<728, 256, 0, stream>>>(feat[0], pos[0], mask[0],
                                   feat[1], pos[1], mask[1],
                                   feat[2], pos[2], mask[2],
                                   feat[3], pos[3], mask[3],
                                   det, Wswz,
                                   cb[0], cb[1], cb[2], cb[3],
                                   lg[0], lb[0], lg[1], lb[1],
                                   lg[2], lb[2], lg[3], lb[3], ctxsum,
                                   lq, Wq, bq, qng, qnb, pooled, flags, qt);
  k_hpre<<<96, 256, 0, stream>>>(qt, ctxsum, W1, b1, hpre);
  k_out<<<52, 256, 0, stream>>>(hpre, W2, b2, out);
}

// Round 13
// 234.299 us; speedup vs baseline: 1.3770x; 1.0238x over previous
//
#include <hip/hip_runtime.h>
#include <hip/hip_bf16.h>

#define Bn 8
#define Qn 300
#define Pn 5
#define RSn 256
#define QSn 768
#define NCn 396
#define MTOT 10880
#define THRL -1.3862943611198906f   // log(0.2/0.8): sigmoid(x)>0.2 <=> x>THRL

typedef __attribute__((ext_vector_type(8))) short short8;
typedef __attribute__((ext_vector_type(4))) float float4v;

__device__ inline float wred(float v){
  #pragma unroll
  for (int off = 32; off; off >>= 1) v += __shfl_xor(v, off);
  return v;
}

__device__ __forceinline__ unsigned short f2bf(float f){
  union { float f; unsigned int u; } c; c.f = f;
  return (unsigned short)((c.u + 0x7FFF + ((c.u >> 16) & 1)) >> 16);   // RNE
}

// =====================================================================
// D1: k_front — [0,160): query-pooling PARTIALS (4 blocks per (b,p),
//   75 q each -> 5-round chains instead of 25; partial sums/counts to
//   psum4/cnt4, combined later in k_pgemm's query blocks);
//   [160,928): convW f32 -> bf16 swizzled Wswz; 928: mask detect;
//   [929,941): zero ctxsum+hpre ; [941,945): zero out
// =====================================================================
__global__ __launch_bounds__(256, 4) void k_front(
    const float* cw0, const float* cw1, const float* cw2, const float* cw3,
    short* Wswz, const int* __restrict__ mk0, int* det,
    const float* __restrict__ pl, const float* __restrict__ hs,
    float* psum4, float* cnt4, float* ctxsum, float* outz){
  int bx = blockIdx.x;
  int t = threadIdx.x;
  if (bx < 160){
    // ---- pooling partial: slot = (b,p), part handles q [part*75, +75)
    __shared__ float mskL[75];
    int slot = bx >> 2, part = bx & 3;
    int bb = slot / Pn, p = slot % Pn;
    int qbase = part * 75;
    if (t < 75)
      mskL[t] = (pl[(bb*Qn + qbase + t)*Pn + p] > THRL) ? 1.f : 0.f;
    __syncthreads();
    const float* hb = hs + ((size_t)bb*Qn + qbase)*RSn + t;
    float sA[15];
    #pragma unroll
    for (int i = 0; i < 15; ++i) sA[i] = 0.f;
    float cnt = 0.f;
    for (int r = 0; r < 5; ++r){
      #pragma unroll
      for (int i = 0; i < 15; ++i){
        float m = mskL[r*15 + i];
        cnt += m;
        sA[i] = fmaf(m, hb[(size_t)(r*15 + i)*RSn], sA[i]);
      }
    }
    float ssum = (((sA[0]+sA[1]) + (sA[2]+sA[3])) + ((sA[4]+sA[5]) + (sA[6]+sA[7])))
               + (((sA[8]+sA[9]) + (sA[10]+sA[11])) + ((sA[12]+sA[13]) + sA[14]));
    psum4[((size_t)part*40 + slot)*256 + t] = ssum;
    if (t == 0) cnt4[part*40 + slot] = cnt;
    return;
  }
  if (bx < 928){
    int cbx = bx - 160;
    int s = cbx / 192;
    int linear = (cbx % 192)*256 + t;
    int q = linear & 63, n = linear >> 6;
    const float* src = (s==0)?cw0:(s==1)?cw1:(s==2)?cw2:cw3;
    float4 f = *(const float4*)(src + (size_t)n*256 + q*4);
    int kc = q >> 3, lk = (q >> 1) & 3, e0 = (q & 1)*4;
    short* dst = Wswz + ((size_t)(s*8 + kc))*24576 + lk*6144 + n*8 + e0;
    short4 sv;
    sv.x = (short)f2bf(f.x); sv.y = (short)f2bf(f.y);
    sv.z = (short)f2bf(f.z); sv.w = (short)f2bf(f.w);
    *(short4*)dst = sv;
    return;
  }
  if (bx == 928){
    __shared__ int r0[4], r1[4];
    const int* mm = mk0 + t*32;
    int d0 = 0, d1 = 0;
    #pragma unroll 8
    for (int i = 0; i < 32; ++i){
      int v = mm[i];
      d0 |= (v != 0 && v != 1);
      d1 |= (v != 0 && v != 0x3F800000);
    }
    unsigned long long bal0 = __ballot(d0), bal1 = __ballot(d1);
    int wid = t >> 6;
    if ((t & 63) == 0){ r0[wid] = (bal0 != 0ull); r1[wid] = (bal1 != 0ull); }
    __syncthreads();
    if (t == 0){
      det[0] = r0[0] | r0[1] | r0[2] | r0[3];
      det[1] = r1[0] | r1[1] | r1[2] | r1[3];
    }
    return;
  }
  if (bx >= 941){
    int idx = ((bx - 941)*256 + t)*4;
    if (idx < Bn*NCn) *(float4*)(outz + idx) = (float4){0.f,0.f,0.f,0.f};
    return;
  }
  // bx in [929,941): zero ctxsum(6144)+hpre(6144)
  {
    int idx = ((bx - 929)*256 + t)*4;
    *(float4*)(ctxsum + idx) = (float4){0.f,0.f,0.f,0.f};
  }
}

// =====================================================================
// D2: k_pgemm — blocks [0,680): fused pool + MFMA GEMM + bias + LN + token-sum
//               blocks [680,728): query tokens + LN -> qt (now also
//               combines the psum4/cnt4 pooling partials inline)
// (round-12 GEMM body — best measured, 239.9 us)
// =====================================================================
__global__ __launch_bounds__(256, 3) void k_pgemm(
    const float* fe0, const float* po0, const void* ma0,
    const float* fe1, const float* po1, const void* ma1,
    const float* fe2, const float* po2, const void* ma2,
    const float* fe3, const float* po3, const void* ma3,
    const int* __restrict__ det, const short* __restrict__ Wswz,
    const float* cb0, const float* cb1, const float* cb2, const float* cb3,
    const float* lg0, const float* lb0, const float* lg1, const float* lb1,
    const float* lg2, const float* lb2, const float* lg3, const float* lb3,
    float* __restrict__ ctxsum,
    const float* __restrict__ lq, const float* __restrict__ Wq,
    const float* __restrict__ bq, const float* __restrict__ qng,
    const float* __restrict__ qnb, const float* __restrict__ psum4,
    const float* __restrict__ cnt4, float* qt){
  __shared__ short As[16*264];        // 8.25 KB A-tile [m][k], pitch 264
  __shared__ float imls[16];
  __shared__ float lsum[4][16], lsq[4][16];
  __shared__ float pq[256];
  __shared__ float s1s[4], s2s[4];
  int blk = blockIdx.x;
  int t = threadIdx.x;

  if (blk >= 680){
    // ---- query tokens + LN (combines pooling partials inline)
    int qbx = blk - 680;
    int b = qbx / 6, j = qbx % 6;
    float v0 = lq[j*QSn + t], v1 = lq[j*QSn + t + 256], v2 = lq[j*QSn + t + 512];
    float ct[5];
    #pragma unroll
    for (int p = 0; p < 5; ++p){
      int sl = b*Pn + p;
      ct[p] = cnt4[sl] + cnt4[40 + sl] + cnt4[80 + sl] + cnt4[120 + sl];
    }
    int any = (ct[0] > 0.f) | (ct[1] > 0.f) | (ct[2] > 0.f) | (ct[3] > 0.f) | (ct[4] > 0.f);
    if (j > 0 && any){
      int sl = b*Pn + (j-1);
      float cs = ct[j-1];
      float ps = psum4[(size_t)sl*256 + t]
               + psum4[((size_t)40 + sl)*256 + t]
               + psum4[((size_t)80 + sl)*256 + t]
               + psum4[((size_t)120 + sl)*256 + t];
      pq[t] = (cs > 0.f) ? ps / cs : 0.f;
      __syncthreads();
      float a0 = 0.f, a1 = 0.f, a2 = 0.f;
      #pragma unroll 8
      for (int c = 0; c < RSn; ++c){
        float pv = pq[c];
        a0 = fmaf(pv, Wq[c*QSn + t      ], a0);
        a1 = fmaf(pv, Wq[c*QSn + t + 256], a1);
        a2 = fmaf(pv, Wq[c*QSn + t + 512], a2);
      }
      v0 += a0 + bq[t]; v1 += a1 + bq[t+256]; v2 += a2 + bq[t+512];
    }
    float sm = v0 + v1 + v2, sq = v0*v0 + v1*v1 + v2*v2;
    sm = wred(sm); sq = wred(sq);
    int wid = t >> 6, lane = t & 63;
    if (lane == 0){ s1s[wid] = sm; s2s[wid] = sq; }
    __syncthreads();
    float S  = s1s[0] + s1s[1] + s1s[2] + s1s[3];
    float SQ = s2s[0] + s2s[1] + s2s[2] + s2s[3];
    float mu = S * (1.f/QSn), var = SQ * (1.f/QSn) - mu*mu;
    float rs = rsqrtf(var + 1e-5f);
    float* o = qt + (b*6 + j)*QSn;
    o[t      ] = (v0 - mu)*rs*qng[t      ] + qnb[t      ];
    o[t + 256] = (v1 - mu)*rs*qng[t + 256] + qnb[t + 256];
    o[t + 512] = (v2 - mu)*rs*qng[t + 512] + qnb[t + 512];
    return;
  }

  int m0 = blk * 16;
  int s, H, OWlog, b0;
  const float *F, *Pp; const void* M;
  const float *CB, *LG, *LB;
  if (m0 < 8192){ s=0; F=fe0; Pp=po0; M=ma0; H=64; OWlog=5; b0=m0>>10;
                  CB=cb0; LG=lg0; LB=lb0; }
  else if (m0 < 10240){ s=1; F=fe1; Pp=po1; M=ma1; H=32; OWlog=4; b0=(m0-8192)>>8;
                  CB=cb1; LG=lg1; LB=lb1; }
  else if (m0 < 10752){ s=2; F=fe2; Pp=po2; M=ma2; H=16; OWlog=3; b0=(m0-10240)>>6;
                  CB=cb2; LG=lg2; LB=lb2; }
  else { s=3; F=fe3; Pp=po3; M=ma3; H=8; OWlog=2; b0=(m0-10752)>>4;
                  CB=cb3; LG=lg3; LB=lb3; }
  int HH = H*H;
  int OWm = (H >> 1) - 1;
  int mode = (det[0] == 0) ? 0 : ((det[1] == 0) ? 2 : 1);

  // ---- token-pair geometry: slotp = t&7 (8 pairs), cg = t>>3 (0..31)
  int slotp = t & 7;
  int cg = t >> 3;
  int mA = m0 + slotp*2;
  int ltl;
  if (s == 0)      ltl = mA & 1023;
  else if (s == 1) ltl = mA & 255;
  else if (s == 2) ltl = mA & 63;
  else             ltl = mA & 15;
  int ph = ltl >> OWlog, pw = ltl & OWm;   // pw even
  int i00 = ph*2*H + pw*2;                 // multiple of 4 -> float4 aligned
  int mbase = b0*HH;

  // ---- mask weights for both tokens of the pair (16B-span reads)
  float w0A,w1A,w2A,w3A, w0B,w1B,w2B,w3B;
  if (mode == 0){
    const int* Mi = (const int*)M + mbase + i00;
    int4 ma = *(const int4*)(Mi);
    int4 mb = *(const int4*)(Mi + H);
    w0A = ma.x?0.f:1.f; w1A = ma.y?0.f:1.f; w2A = mb.x?0.f:1.f; w3A = mb.y?0.f:1.f;
    w0B = ma.z?0.f:1.f; w1B = ma.w?0.f:1.f; w2B = mb.z?0.f:1.f; w3B = mb.w?0.f:1.f;
  } else if (mode == 1){
    const unsigned char* Mb = (const unsigned char*)M + mbase + i00;
    uchar4 av = *(const uchar4*)(Mb);
    uchar4 bv = *(const uchar4*)(Mb + H);
    w0A = av.x?0.f:1.f; w1A = av.y?0.f:1.f; w2A = bv.x?0.f:1.f; w3A = bv.y?0.f:1.f;
    w0B = av.z?0.f:1.f; w1B = av.w?0.f:1.f; w2B = bv.z?0.f:1.f; w3B = bv.w?0.f:1.f;
  } else {
    const float* Mf = (const float*)M + mbase + i00;
    float4 ma = *(const float4*)(Mf);
    float4 mb = *(const float4*)(Mf + H);
    w0A = 1.f-ma.x; w1A = 1.f-ma.y; w2A = 1.f-mb.x; w3A = 1.f-mb.y;
    w0B = 1.f-ma.z; w1B = 1.f-ma.w; w2B = 1.f-mb.z; w3B = 1.f-mb.w;
  }
  float msA = w0A+w1A+w2A+w3A, msB = w0B+w1B+w2B+w3B;
  float imA = 1.f / fmaxf(msA*0.25f, 1e-6f);
  float imB = 1.f / fmaxf(msB*0.25f, 1e-6f);
  float scA = 0.25f*imA, scB = 0.25f*imB;
  if (t < 8){ imls[t*2] = imA; imls[t*2 + 1] = imB; }

  // ---- pool 256 channels into As[m][k]: 8 fully-unrolled rounds of
  // 4 float4 loads (token-pair: xA from .x/.y, xB from .z/.w)
  {
    size_t base = (size_t)(b0*256 + cg)*HH + i00;
    const float* Fp = F + base;
    const float* Pq2 = Pp + base;
    const size_t stride = (size_t)32*HH;
    int rowA = slotp*2*264, rowB = rowA + 264;
    #pragma unroll
    for (int r = 0; r < 8; ++r){
      float4 f0 = *(const float4*)(Fp);
      float4 f1 = *(const float4*)(Fp + H);
      float4 p0 = *(const float4*)(Pq2);
      float4 p1 = *(const float4*)(Pq2 + H);
      float xA = (f0.x+p0.x)*w0A + (f0.y+p0.y)*w1A + (f1.x+p1.x)*w2A + (f1.y+p1.y)*w3A;
      float xB = (f0.z+p0.z)*w0B + (f0.w+p0.w)*w1B + (f1.z+p1.z)*w2B + (f1.w+p1.w)*w3B;
      As[rowA + cg + r*32] = (short)f2bf(xA*scA);
      As[rowB + cg + r*32] = (short)f2bf(xB*scB);
      Fp += stride; Pq2 += stride;
    }
  }
  __syncthreads();

  // ---- A fragments to registers
  int wid = t >> 6, l = t & 63;
  int lm = l & 15, lk = l >> 4;
  int nfb = wid * 12;
  short8 aReg[8];
  #pragma unroll
  for (int kc = 0; kc < 8; ++kc)
    aReg[kc] = *(const short8*)(As + lm*264 + kc*32 + lk*8);

  float4v acc[12];
  #pragma unroll
  for (int nf = 0; nf < 12; ++nf) acc[nf] = (float4v){0.f,0.f,0.f,0.f};

  // ---- K loop: B fragments straight from L2 (pre-swizzled, 16B/lane)
  const short* Bb = Wswz + ((size_t)(s*8))*24576 + lk*6144 + nfb*128 + lm*8;
  #pragma unroll
  for (int kc = 0; kc < 8; ++kc){
    const short* bp = Bb + kc*24576;
    #pragma unroll
    for (int nf = 0; nf < 12; ++nf){
      short8 bf = *(const short8*)(bp + nf*128);
      acc[nf] = __builtin_amdgcn_mfma_f32_16x16x32_bf16(aReg[kc], bf, acc[nf], 0, 0, 0);
    }
  }

  // ---- epilogue: bias (via LDS im), per-row LN, token-sum -> ctxsum
  float im4[4];
  #pragma unroll
  for (int r = 0; r < 4; ++r) im4[r] = imls[lk*4 + r];

  float sum[4] = {0,0,0,0}, sq[4] = {0,0,0,0};
  #pragma unroll
  for (int nf = 0; nf < 12; ++nf){
    float cbv = CB[(nfb+nf)*16 + lm];
    #pragma unroll
    for (int r = 0; r < 4; ++r){
      float p = acc[nf][r] + cbv*im4[r];
      acc[nf][r] = p;
      sum[r] += p;
      sq[r] = fmaf(p, p, sq[r]);
    }
  }
  #pragma unroll
  for (int r = 0; r < 4; ++r){
    #pragma unroll
    for (int off = 1; off < 16; off <<= 1){
      sum[r] += __shfl_xor(sum[r], off);
      sq[r]  += __shfl_xor(sq[r],  off);
    }
  }
  if (lm == 0){
    #pragma unroll
    for (int r = 0; r < 4; ++r){
      lsum[wid][lk*4 + r] = sum[r];
      lsq[wid][lk*4 + r]  = sq[r];
    }
  }
  __syncthreads();
  float mu[4], rs[4];
  #pragma unroll
  for (int r = 0; r < 4; ++r){
    int row = lk*4 + r;
    float S  = lsum[0][row] + lsum[1][row] + lsum[2][row] + lsum[3][row];
    float SQ = lsq[0][row]  + lsq[1][row]  + lsq[2][row]  + lsq[3][row];
    mu[r] = S * (1.f/768.f);
    float var = SQ * (1.f/768.f) - mu[r]*mu[r];
    rs[r] = rsqrtf(var + 1e-5f);
  }
  #pragma unroll
  for (int nf = 0; nf < 12; ++nf){
    int n = (nfb+nf)*16 + lm;
    float g = LG[n], bv = LB[n];
    float tv = 0.f;
    #pragma unroll
    for (int r = 0; r < 4; ++r)
      tv += (acc[nf][r] - mu[r]) * rs[r];
    tv = tv*g + 4.f*bv;
    tv += __shfl_xor(tv, 16); tv += __shfl_xor(tv, 32);
    if (lk == 0)
      atomicAdd(&ctxsum[b0*768 + n], tv);
  }
}

// =====================================================================
// D3: k_hpre — hpre += v @ W1 (+b1). Grid 96 = 24n(32col) x 4k(192c).
// 16 partial accumulators (round-8 ILP win).
// =====================================================================
__global__ void k_hpre(const float* __restrict__ qt, const float* __restrict__ ctxsum,
                       const float* __restrict__ W1, const float* __restrict__ b1,
                       float* __restrict__ hpre){
  __shared__ float vsh[Bn][192];
  int nc = blockIdx.x % 24, kc = blockIdx.x / 24;
  int n0 = nc*32, c0 = kc*192;
  int t = threadIdx.x;
  for (int i = t; i < Bn*192; i += 256){
    int b = i / 192, cl = i - b*192;
    int c = c0 + cl;
    const float* q = qt + (size_t)b*6*768;
    float pm = q[768+c] + q[2*768+c] + q[3*768+c] + q[4*768+c] + q[5*768+c];
    vsh[b][cl] = q[c] + 0.2f*pm + ctxsum[b*768 + c]*(1.f/680.f);
  }
  __syncthreads();
  int ow = t & 31, bi = t >> 5;
  int o = n0 + ow;
  const float* w = W1 + (size_t)c0*768 + o;
  float pacc[16];
  #pragma unroll
  for (int i = 0; i < 16; ++i) pacc[i] = 0.f;
  for (int cl = 0; cl < 192; cl += 16){
    #pragma unroll
    for (int i = 0; i < 16; ++i)
      pacc[i] = fmaf(vsh[bi][cl + i], w[(size_t)(cl + i)*768], pacc[i]);
  }
  float acc = ((pacc[0]+pacc[1])+(pacc[2]+pacc[3])) + ((pacc[4]+pacc[5])+(pacc[6]+pacc[7]))
            + ((pacc[8]+pacc[9])+(pacc[10]+pacc[11])) + ((pacc[12]+pacc[13])+(pacc[14]+pacc[15]));
  if (kc == 0) acc += b1[o];
  atomicAdd(&hpre[bi*768 + o], acc);
}

// =====================================================================
// D4: k_out — out += relu(hpre) @ W2 (+b2). Grid 52 = 13n(32) x 4k(192).
// =====================================================================
__global__ void k_out(const float* __restrict__ hpre, const float* __restrict__ W2,
                      const float* __restrict__ b2, float* __restrict__ out){
  __shared__ float hsh[Bn][192];
  int nc = blockIdx.x % 13, kc = blockIdx.x / 13;
  int n0 = nc*32, c0 = kc*192;
  int t = threadIdx.x;
  for (int i = t; i < Bn*192; i += 256){
    int b = i / 192, cl = i - b*192;
    hsh[b][cl] = fmaxf(hpre[b*768 + c0 + cl], 0.f);
  }
  __syncthreads();
  int ow = t & 31, bi = t >> 5;
  int o = n0 + ow;
  if (o >= NCn) return;
  const float* w = W2 + (size_t)c0*NCn + o;
  float pacc[16];
  #pragma unroll
  for (int i = 0; i < 16; ++i) pacc[i] = 0.f;
  for (int cl = 0; cl < 192; cl += 16){
    #pragma unroll
    for (int i = 0; i < 16; ++i)
      pacc[i] = fmaf(hsh[bi][cl + i], w[(size_t)(cl + i)*NCn], pacc[i]);
  }
  float acc = ((pacc[0]+pacc[1])+(pacc[2]+pacc[3])) + ((pacc[4]+pacc[5])+(pacc[6]+pacc[7]))
            + ((pacc[8]+pacc[9])+(pacc[10]+pacc[11])) + ((pacc[12]+pacc[13])+(pacc[14]+pacc[15]));
  if (kc == 0) acc += b2[o];
  atomicAdd(&out[bi*NCn + o], acc);
}

extern "C" void kernel_launch(void* const* d_in, const int* in_sizes, int n_in,
                              void* d_out, int out_size, void* d_ws, size_t ws_size,
                              hipStream_t stream){
  const float* pl = (const float*)d_in[0];
  const float* hs = (const float*)d_in[2];
  const float* feat[4]; const float* pos[4]; const void* mask[4];
  const float* cw[4]; const float* cb[4]; const float* lg[4]; const float* lb[4];
  for (int s = 0; s < 4; ++s){
    int base = 3 + 7*s;
    feat[s] = (const float*)d_in[base];
    pos[s]  = (const float*)d_in[base+1];
    mask[s] = d_in[base+2];
    cw[s]   = (const float*)d_in[base+3];
    cb[s]   = (const float*)d_in[base+4];
    lg[s]   = (const float*)d_in[base+5];
    lb[s]   = (const float*)d_in[base+6];
  }
  const float* lq  = (const float*)d_in[31];
  const float* Wq  = (const float*)d_in[32];
  const float* bq  = (const float*)d_in[33];
  const float* qng = (const float*)d_in[34];
  const float* qnb = (const float*)d_in[35];
  const float* W1  = (const float*)d_in[36];
  const float* b1  = (const float*)d_in[37];
  const float* W2  = (const float*)d_in[38];
  const float* b2  = (const float*)d_in[39];
  float* out = (float*)d_out;

  // ---- workspace layout (~1.95 MB)
  short* Wswz   = (short*)d_ws;                        // [4][8][4][768][8] bf16 = 1.5 MB
  float* qt     = (float*)(Wswz + (size_t)4*8*4*768*8);// 8*6*768
  float* ctxsum = qt + Bn*6*QSn;                       // 8*768 (zeroed by k_front)
  float* hpre   = ctxsum + Bn*QSn;                     // 8*768 (zeroed by k_front)
  float* psum4  = hpre + Bn*QSn;                       // [4][40][256] pooling partials
  float* cnt4   = psum4 + 4*40*256;                    // [4][40] partial counts
  int*   det    = (int*)(cnt4 + 160);                  // 2 ints

  k_front<<<945, 256, 0, stream>>>(cw[0], cw[1], cw[2], cw[3], Wswz,
                                   (const int*)mask[0], det, pl, hs, psum4, cnt4,
                                   ctxsum, out);
  k_pgemm<<<728, 256, 0, stream>>>(feat[0], pos[0], mask[0],
                                   feat[1], pos[1], mask[1],
                                   feat[2], pos[2], mask[2],
                                   feat[3], pos[3], mask[3],
                                   det, Wswz,
                                   cb[0], cb[1], cb[2], cb[3],
                                   lg[0], lb[0], lg[1], lb[1],
                                   lg[2], lb[2], lg[3], lb[3], ctxsum,
                                   lq, Wq, bq, qng, qnb, psum4, cnt4, qt);
  k_hpre<<<96, 256, 0, stream>>>(qt, ctxsum, W1, b1, hpre);
  k_out<<<52, 256, 0, stream>>>(hpre, W2, b2, out);
}